// Round 1
// baseline (55.544 us; speedup 1.0000x reference)
//
#include <hip/hip_runtime.h>

#define N 4096
#define MASK 4095
#define K1_ROWS 16
#define K1_BLOCKS (N / K1_ROWS)   // 256

// ---------------------------------------------------------------------------
// K1: fused single pass over km1 and km2.
//   block = 256 threads, each block handles K1_ROWS consecutive rows, all cols.
//   Per row j:  dp = sum_k key[(k-j)&4095] * km[j,k]  -> wave-reduce -> dpart
//   Across rows: tp[col] += o[j] * km[j,col]          -> tpart (per-block slice)
// ---------------------------------------------------------------------------
__global__ __launch_bounds__(256) void k1_fused(
    const float* __restrict__ key,
    const float* __restrict__ km1, const float* __restrict__ km2,
    const float* __restrict__ o1, const float* __restrict__ o2,
    float* __restrict__ tpart1, float* __restrict__ tpart2,
    float* __restrict__ dpart1, float* __restrict__ dpart2)
{
    __shared__ float skey[4096 + 128];   // +1 pad per 32 -> conflict-free stride-4 gather
    const int t = threadIdx.x;
    const int b = blockIdx.x;

    // stage key into padded LDS (coalesced global reads)
    #pragma unroll
    for (int q = 0; q < 16; ++q) {
        int idx = q * 256 + t;
        skey[idx + (idx >> 5)] = key[idx];
    }
    __syncthreads();

    float tp1[16], tp2[16];
    #pragma unroll
    for (int i = 0; i < 16; ++i) { tp1[i] = 0.f; tp2[i] = 0.f; }

    const int j0 = b * K1_ROWS;
    const int lane = t & 63;
    const int wave = t >> 6;

    for (int r = 0; r < K1_ROWS; ++r) {
        const int j = j0 + r;
        const float4* row1 = (const float4*)(km1 + (size_t)j * N);
        const float4* row2 = (const float4*)(km2 + (size_t)j * N);
        float4 a1[4], a2[4];
        #pragma unroll
        for (int c = 0; c < 4; ++c) {
            a1[c] = row1[c * 256 + t];
            a2[c] = row2[c * 256 + t];
        }
        const float o1j = o1[j];
        const float o2j = o2[j];

        float dp1 = 0.f, dp2 = 0.f;
        #pragma unroll
        for (int c = 0; c < 4; ++c) {
            const int col0 = c * 1024 + t * 4;
            const float* v1 = (const float*)&a1[c];
            const float* v2 = (const float*)&a2[c];
            #pragma unroll
            for (int i = 0; i < 4; ++i) {
                int w = (col0 + i - j) & MASK;
                float kv = skey[w + (w >> 5)];
                dp1 += kv * v1[i];
                dp2 += kv * v2[i];
                tp1[c * 4 + i] += o1j * v1[i];
                tp2[c * 4 + i] += o2j * v2[i];
            }
        }
        // wave-level reduction (64 lanes)
        #pragma unroll
        for (int off = 32; off > 0; off >>= 1) {
            dp1 += __shfl_down(dp1, off, 64);
            dp2 += __shfl_down(dp2, off, 64);
        }
        if (lane == 0) {
            dpart1[j * 4 + wave] = dp1;
            dpart2[j * 4 + wave] = dp2;
        }
    }

    // write per-block column partials (coalesced float4 stores)
    float4* tp1o = (float4*)(tpart1 + (size_t)b * N);
    float4* tp2o = (float4*)(tpart2 + (size_t)b * N);
    #pragma unroll
    for (int c = 0; c < 4; ++c) {
        tp1o[c * 256 + t] = make_float4(tp1[c*4], tp1[c*4+1], tp1[c*4+2], tp1[c*4+3]);
        tp2o[c * 256 + t] = make_float4(tp2[c*4], tp2[c*4+1], tp2[c*4+2], tp2[c*4+3]);
    }
}

// ---------------------------------------------------------------------------
// K2: reduce partials.
//   blocks 0..127  : t1/t2 column sums over 256 slices (64 cols per block)
//   blocks 128..191: d1/d2 sums over 4 wave-partials (64 rows per block)
// ---------------------------------------------------------------------------
__global__ __launch_bounds__(64) void k2_reduce(
    const float* __restrict__ tpart1, const float* __restrict__ tpart2,
    const float* __restrict__ dpart1, const float* __restrict__ dpart2,
    float* __restrict__ t1, float* __restrict__ t2,
    float* __restrict__ d1, float* __restrict__ d2)
{
    const int b = blockIdx.x;
    const int t = threadIdx.x;
    if (b < 128) {
        const float* src = (b < 64) ? tpart1 : tpart2;
        float* dst       = (b < 64) ? t1 : t2;
        const int col = (b & 63) * 64 + t;
        float acc0 = 0.f, acc1 = 0.f, acc2 = 0.f, acc3 = 0.f;
        for (int s = 0; s < K1_BLOCKS; s += 4) {
            acc0 += src[(size_t)(s + 0) * N + col];
            acc1 += src[(size_t)(s + 1) * N + col];
            acc2 += src[(size_t)(s + 2) * N + col];
            acc3 += src[(size_t)(s + 3) * N + col];
        }
        dst[col] = (acc0 + acc1) + (acc2 + acc3);
    } else {
        const int row = (b - 128) * 64 + t;
        d1[row] = (dpart1[row*4] + dpart1[row*4+1]) + (dpart1[row*4+2] + dpart1[row*4+3]);
        d2[row] = (dpart2[row*4] + dpart2[row*4+1]) + (dpart2[row*4+2] + dpart2[row*4+3]);
    }
}

// ---------------------------------------------------------------------------
// K3: three circulant matvecs + final combine.
//   1 wave per block, 4 rows per wave, grid 1024. Vectors are L1/L2-hot.
//   result[j] = (base[j] - (q1[j]-d1[j]*o1[j]) - (q2[j]-d2[j]*o2[j])) / d1[j]
//   out[N] = d2[N-1]
// ---------------------------------------------------------------------------
__global__ __launch_bounds__(64) void k3_final(
    const float* __restrict__ key, const float* __restrict__ x,
    const float* __restrict__ t1, const float* __restrict__ t2,
    const float* __restrict__ d1, const float* __restrict__ d2,
    const float* __restrict__ o1, const float* __restrict__ o2,
    float* __restrict__ out)
{
    const int lane = threadIdx.x;
    const int j0 = blockIdx.x * 4;

    float accb[4] = {0.f, 0.f, 0.f, 0.f};
    float acc1[4] = {0.f, 0.f, 0.f, 0.f};
    float acc2[4] = {0.f, 0.f, 0.f, 0.f};

    for (int c = 0; c < 64; ++c) {
        const int k = c * 64 + lane;
        const float xv  = x[k];
        const float t1v = t1[k];
        const float t2v = t2[k];
        #pragma unroll
        for (int r = 0; r < 4; ++r) {
            const float kv = key[(k - (j0 + r)) & MASK];
            accb[r] += kv * xv;
            acc1[r] += kv * t1v;
            acc2[r] += kv * t2v;
        }
    }

    #pragma unroll
    for (int r = 0; r < 4; ++r) {
        float vb = accb[r], v1 = acc1[r], v2 = acc2[r];
        #pragma unroll
        for (int off = 32; off > 0; off >>= 1) {
            vb += __shfl_down(vb, off, 64);
            v1 += __shfl_down(v1, off, 64);
            v2 += __shfl_down(v2, off, 64);
        }
        if (lane == 0) {
            const int j = j0 + r;
            const float dd1 = d1[j];
            const float dd2 = d2[j];
            const float r2 = v1 - dd1 * o1[j];
            const float r4 = v2 - dd2 * o2[j];
            out[j] = (vb - r2 - r4) / dd1;
            if (j == N - 1) out[N] = dd2;   // redun3 = d2[last row]
        }
    }
}

extern "C" void kernel_launch(void* const* d_in, const int* in_sizes, int n_in,
                              void* d_out, int out_size, void* d_ws, size_t ws_size,
                              hipStream_t stream) {
    const float* key = (const float*)d_in[0];
    const float* x   = (const float*)d_in[1];
    const float* km1 = (const float*)d_in[2];
    const float* o1  = (const float*)d_in[3];
    const float* km2 = (const float*)d_in[4];
    const float* o2  = (const float*)d_in[5];
    float* out = (float*)d_out;

    float* ws = (float*)d_ws;
    float* tpart1 = ws;                                  // 256*4096
    float* tpart2 = tpart1 + (size_t)K1_BLOCKS * N;      // 256*4096
    float* dpart1 = tpart2 + (size_t)K1_BLOCKS * N;      // 4096*4
    float* dpart2 = dpart1 + (size_t)N * 4;              // 4096*4
    float* t1     = dpart2 + (size_t)N * 4;              // 4096
    float* t2     = t1 + N;
    float* d1     = t2 + N;
    float* d2     = d1 + N;

    hipLaunchKernelGGL(k1_fused, dim3(K1_BLOCKS), dim3(256), 0, stream,
                       key, km1, km2, o1, o2, tpart1, tpart2, dpart1, dpart2);
    hipLaunchKernelGGL(k2_reduce, dim3(192), dim3(64), 0, stream,
                       tpart1, tpart2, dpart1, dpart2, t1, t2, d1, d2);
    hipLaunchKernelGGL(k3_final, dim3(1024), dim3(64), 0, stream,
                       key, x, t1, t2, d1, d2, o1, o2, out);
}

// Round 2
// 44.747 us; speedup vs baseline: 1.2413x; 1.2413x over previous
//
#include <hip/hip_runtime.h>

#define N 4096
#define MASK 4095

// ---------------------------------------------------------------------------
// K1: fused single pass over km1 and km2.
//   2048 blocks x 256 threads: rc = b>>3 owns 16 rows, cc = b&7 owns 512 cols.
//   Per row j:  dp = sum_col key[(col-j)&4095] * km[j,col] -> wave-reduce
//               -> dpart[j][cc*4+wave]   (32 slices per row)
//   Across rows: tp[col] += o[j]*km[j,col] -> tpart[rc][col] (256 slices/col)
// ---------------------------------------------------------------------------
__global__ __launch_bounds__(256) void k1_fused(
    const float* __restrict__ key,
    const float* __restrict__ km1, const float* __restrict__ km2,
    const float* __restrict__ o1, const float* __restrict__ o2,
    float* __restrict__ tpart1, float* __restrict__ tpart2,
    float* __restrict__ dpart1, float* __restrict__ dpart2)
{
    __shared__ float skey[544];          // 527 window + 1-per-32 padding
    const int t = threadIdx.x;
    const int b = blockIdx.x;
    const int rc = b >> 3;               // row chunk: 16 rows
    const int cc = b & 7;                // col chunk: 512 cols
    const int j0 = rc * 16;
    const int c0 = cc * 512;
    const int base = c0 - j0 - 15;       // lowest (col - j) used by this block

    // stage key window: idx in [0,526] maps to key[(base+idx)&4095]
    for (int i = t; i < 527; i += 256) {
        skey[i + (i >> 5)] = key[(base + i) & MASK];
    }
    __syncthreads();

    const int wave = t >> 6;
    const int lane = t & 63;

    float tp1x = 0.f, tp1y = 0.f, tp2x = 0.f, tp2y = 0.f;

    #pragma unroll
    for (int r = 0; r < 16; ++r) {
        const int j = j0 + r;
        const float2 m1 = ((const float2*)(km1 + (size_t)j * N + c0))[t];
        const float2 m2 = ((const float2*)(km2 + (size_t)j * N + c0))[t];

        // key indices for cols c0+2t, c0+2t+1:  idx = 2t + 15 - r (+1)
        const int i0 = 2 * t + 15 - r;
        const int i1 = i0 + 1;
        const float kv0 = skey[i0 + (i0 >> 5)];
        const float kv1 = skey[i1 + (i1 >> 5)];

        float dp1 = kv0 * m1.x + kv1 * m1.y;
        float dp2 = kv0 * m2.x + kv1 * m2.y;

        const float o1j = o1[j];   // uniform across block -> scalar load
        const float o2j = o2[j];
        tp1x += o1j * m1.x; tp1y += o1j * m1.y;
        tp2x += o2j * m2.x; tp2y += o2j * m2.y;

        #pragma unroll
        for (int off = 32; off > 0; off >>= 1) {
            dp1 += __shfl_down(dp1, off, 64);
            dp2 += __shfl_down(dp2, off, 64);
        }
        if (lane == 0) {
            dpart1[(size_t)j * 32 + cc * 4 + wave] = dp1;
            dpart2[(size_t)j * 32 + cc * 4 + wave] = dp2;
        }
    }

    ((float2*)(tpart1 + (size_t)rc * N + c0))[t] = make_float2(tp1x, tp1y);
    ((float2*)(tpart2 + (size_t)rc * N + c0))[t] = make_float2(tp2x, tp2y);
}

// ---------------------------------------------------------------------------
// K2: reduce partials. grid = 1280 x 256.
//   blocks [0,256):    t-reduce. Block owns 32 cols of t1 or t2; thread
//                      (sg=t>>5, col=t&31) sums slices sg, sg+8, ... (32 each),
//                      LDS-combine the 8 groups.
//   blocks [256,1280): d-reduce. Block owns 8 rows; thread (row=t>>5, s=t&31)
//                      reads dpart[row*32+s] (fully coalesced), 32-lane shuffle.
// ---------------------------------------------------------------------------
__global__ __launch_bounds__(256) void k2_reduce(
    const float* __restrict__ tpart1, const float* __restrict__ tpart2,
    const float* __restrict__ dpart1, const float* __restrict__ dpart2,
    float* __restrict__ t1, float* __restrict__ t2,
    float* __restrict__ d1, float* __restrict__ d2)
{
    __shared__ float sdata[256];
    const int b = blockIdx.x;
    const int t = threadIdx.x;

    if (b < 256) {
        const float* src = (b < 128) ? tpart1 : tpart2;
        float* dst       = (b < 128) ? t1 : t2;
        const int colbase = (b & 127) * 32;
        const int col = t & 31;
        const int sg = t >> 5;
        float a0 = 0.f, a1 = 0.f, a2 = 0.f, a3 = 0.f;
        #pragma unroll 4
        for (int k = 0; k < 32; k += 4) {
            a0 += src[(size_t)(sg + 8 * (k + 0)) * N + colbase + col];
            a1 += src[(size_t)(sg + 8 * (k + 1)) * N + colbase + col];
            a2 += src[(size_t)(sg + 8 * (k + 2)) * N + colbase + col];
            a3 += src[(size_t)(sg + 8 * (k + 3)) * N + colbase + col];
        }
        sdata[t] = (a0 + a1) + (a2 + a3);
        __syncthreads();
        if (t < 32) {
            float s = 0.f;
            #pragma unroll
            for (int i = 0; i < 8; ++i) s += sdata[i * 32 + t];
            dst[colbase + t] = s;
        }
    } else {
        const int db = b - 256;
        const float* src = (db < 512) ? dpart1 : dpart2;
        float* dst       = (db < 512) ? d1 : d2;
        const int rowbase = (db & 511) * 8;
        const int row = rowbase + (t >> 5);
        const int s = t & 31;
        float v = src[(size_t)row * 32 + s];
        #pragma unroll
        for (int off = 16; off > 0; off >>= 1) v += __shfl_down(v, off, 32);
        if (s == 0) dst[row] = v;
    }
}

// ---------------------------------------------------------------------------
// K3: three circulant matvecs + final combine. One block per output row.
//   result[j] = (base[j] - (q1[j]-d1[j]*o1[j]) - (q2[j]-d2[j]*o2[j])) / d1[j]
//   out[N] = d2[N-1]
// ---------------------------------------------------------------------------
__global__ __launch_bounds__(256) void k3_final(
    const float* __restrict__ key, const float* __restrict__ x,
    const float* __restrict__ t1, const float* __restrict__ t2,
    const float* __restrict__ d1, const float* __restrict__ d2,
    const float* __restrict__ o1, const float* __restrict__ o2,
    float* __restrict__ out)
{
    __shared__ float sd[12];
    const int j = blockIdx.x;
    const int t = threadIdx.x;

    float ab = 0.f, a1 = 0.f, a2 = 0.f;
    #pragma unroll
    for (int q = 0; q < 16; ++q) {
        const int k = q * 256 + t;
        const float kv = key[(k - j) & MASK];   // consecutive lanes -> coalesced
        ab += kv * x[k];
        a1 += kv * t1[k];
        a2 += kv * t2[k];
    }
    #pragma unroll
    for (int off = 32; off > 0; off >>= 1) {
        ab += __shfl_down(ab, off, 64);
        a1 += __shfl_down(a1, off, 64);
        a2 += __shfl_down(a2, off, 64);
    }
    const int wave = t >> 6;
    const int lane = t & 63;
    if (lane == 0) { sd[wave * 3 + 0] = ab; sd[wave * 3 + 1] = a1; sd[wave * 3 + 2] = a2; }
    __syncthreads();
    if (t == 0) {
        const float vb = sd[0] + sd[3] + sd[6] + sd[9];
        const float v1 = sd[1] + sd[4] + sd[7] + sd[10];
        const float v2 = sd[2] + sd[5] + sd[8] + sd[11];
        const float dd1 = d1[j];
        const float dd2 = d2[j];
        const float r2 = v1 - dd1 * o1[j];
        const float r4 = v2 - dd2 * o2[j];
        out[j] = (vb - r2 - r4) / dd1;
        if (j == N - 1) out[N] = dd2;   // redun3 = d2[last row]
    }
}

extern "C" void kernel_launch(void* const* d_in, const int* in_sizes, int n_in,
                              void* d_out, int out_size, void* d_ws, size_t ws_size,
                              hipStream_t stream) {
    const float* key = (const float*)d_in[0];
    const float* x   = (const float*)d_in[1];
    const float* km1 = (const float*)d_in[2];
    const float* o1  = (const float*)d_in[3];
    const float* km2 = (const float*)d_in[4];
    const float* o2  = (const float*)d_in[5];
    float* out = (float*)d_out;

    float* ws = (float*)d_ws;
    float* tpart1 = ws;                                  // 256*4096
    float* tpart2 = tpart1 + (size_t)256 * N;            // 256*4096
    float* dpart1 = tpart2 + (size_t)256 * N;            // 4096*32
    float* dpart2 = dpart1 + (size_t)N * 32;             // 4096*32
    float* t1     = dpart2 + (size_t)N * 32;             // 4096
    float* t2     = t1 + N;
    float* d1     = t2 + N;
    float* d2     = d1 + N;

    hipLaunchKernelGGL(k1_fused, dim3(2048), dim3(256), 0, stream,
                       key, km1, km2, o1, o2, tpart1, tpart2, dpart1, dpart2);
    hipLaunchKernelGGL(k2_reduce, dim3(1280), dim3(256), 0, stream,
                       tpart1, tpart2, dpart1, dpart2, t1, t2, d1, d2);
    hipLaunchKernelGGL(k3_final, dim3(N), dim3(256), 0, stream,
                       key, x, t1, t2, d1, d2, o1, o2, out);
}

// Round 3
// 35.271 us; speedup vs baseline: 1.5748x; 1.2687x over previous
//
#include <hip/hip_runtime.h>

#define N 4096
#define MASK 4095

// ---------------------------------------------------------------------------
// Cross-lane merge-tree reduction:
//   fold(u,v,m): after shfl_xor(m), lanes with (lane&m)==0 hold u-pair-sums,
//   lanes with (lane&m)!=0 hold v-pair-sums.
//   greduce4 reduces 4 independent 64-lane sums in 7 shuffles.
//   Result mapping: lane-group sg = lane>>4:  sg0->g0, sg1->g2, sg2->g1, sg3->g3
//   (offset table 0x3120).
// ---------------------------------------------------------------------------
__device__ __forceinline__ float fold(float u, float v, int m) {
    const bool hi = (threadIdx.x & m) != 0;
    const float t = hi ? u : v;
    const float s = __shfl_xor(t, m, 64);
    return (hi ? v : u) + s;
}

__device__ __forceinline__ float greduce4(float g0, float g1, float g2, float g3) {
    float c1 = fold(g0, g1, 32);
    float c2 = fold(g2, g3, 32);
    float e  = fold(c1, c2, 16);
    e += __shfl_xor(e, 8, 64);
    e += __shfl_xor(e, 4, 64);
    e += __shfl_xor(e, 2, 64);
    e += __shfl_xor(e, 1, 64);
    return e;
}

// ---------------------------------------------------------------------------
// K1: fused single pass over km1 and km2. 2048 blocks x 256 threads.
//   rc = b>>3 owns 16 rows, cc = b&7 owns 512 cols (2 cols/thread, float2).
//   Rows processed in 4-row double-buffered batches: 8 loads always in
//   flight, reductions (register merge-tree) off the load path.
// ---------------------------------------------------------------------------
__global__ __launch_bounds__(256) void k1_fused(
    const float* __restrict__ key,
    const float* __restrict__ km1, const float* __restrict__ km2,
    const float* __restrict__ o1, const float* __restrict__ o2,
    float* __restrict__ tpart1, float* __restrict__ tpart2,
    float* __restrict__ dpart1, float* __restrict__ dpart2)
{
    __shared__ float skey[544];
    const int t = threadIdx.x;
    const int b = blockIdx.x;
    const int rc = b >> 3;
    const int cc = b & 7;
    const int j0 = rc * 16;
    const int c0 = cc * 512;
    const int base = c0 - j0 - 15;     // lowest (col - j) used by this block

    for (int i = t; i < 527; i += 256)
        skey[i + (i >> 5)] = key[(base + i) & MASK];
    __syncthreads();

    // key window in registers: w[c] = key[(base + 2t + c) & 4095]
    // row j0+r, col c0+2t+cx  ->  w[cx + 15 - r]
    float w[17];
    #pragma unroll
    for (int c = 0; c < 17; ++c) {
        const int idx = 2 * t + c;
        w[c] = skey[idx + (idx >> 5)];
    }

    const float2* q1 = (const float2*)(km1 + (size_t)j0 * N + c0);
    const float2* q2 = (const float2*)(km2 + (size_t)j0 * N + c0);

    float2 La[2][4], Lb[2][4];
    #pragma unroll
    for (int i = 0; i < 4; ++i) La[0][i] = q1[(size_t)i * 2048 + t];
    #pragma unroll
    for (int i = 0; i < 4; ++i) Lb[0][i] = q2[(size_t)i * 2048 + t];

    float tp1x = 0.f, tp1y = 0.f, tp2x = 0.f, tp2y = 0.f;
    float rd1[4], rd2[4];

    #pragma unroll
    for (int rb = 0; rb < 4; ++rb) {
        const int cur = rb & 1, nxt = cur ^ 1;
        if (rb < 3) {
            #pragma unroll
            for (int i = 0; i < 4; ++i) La[nxt][i] = q1[(size_t)((rb + 1) * 4 + i) * 2048 + t];
            #pragma unroll
            for (int i = 0; i < 4; ++i) Lb[nxt][i] = q2[(size_t)((rb + 1) * 4 + i) * 2048 + t];
        }
        float dpa[4], dpb[4];
        #pragma unroll
        for (int rr = 0; rr < 4; ++rr) {
            const int r = rb * 4 + rr;
            const float k0 = w[15 - r], k1v = w[16 - r];
            dpa[rr] = k0 * La[cur][rr].x + k1v * La[cur][rr].y;
            dpb[rr] = k0 * Lb[cur][rr].x + k1v * Lb[cur][rr].y;
            const float oa = o1[j0 + r], ob = o2[j0 + r];
            tp1x += oa * La[cur][rr].x; tp1y += oa * La[cur][rr].y;
            tp2x += ob * Lb[cur][rr].x; tp2y += ob * Lb[cur][rr].y;
        }
        rd1[rb] = greduce4(dpa[0], dpa[1], dpa[2], dpa[3]);
        rd2[rb] = greduce4(dpb[0], dpb[1], dpb[2], dpb[3]);
    }

    const int lane = t & 63, wave = t >> 6, sg = lane >> 4;
    const int off = (0x3120 >> (sg * 4)) & 0xF;   // row offset this lane holds
    if ((lane & 15) == 0) {
        #pragma unroll
        for (int qq = 0; qq < 4; ++qq) {
            dpart1[(size_t)(j0 + 4 * qq + off) * 32 + cc * 4 + wave] = rd1[qq];
            dpart2[(size_t)(j0 + 4 * qq + off) * 32 + cc * 4 + wave] = rd2[qq];
        }
    }

    ((float2*)(tpart1 + (size_t)rc * N + c0))[t] = make_float2(tp1x, tp1y);
    ((float2*)(tpart2 + (size_t)rc * N + c0))[t] = make_float2(tp2x, tp2y);
}

// ---------------------------------------------------------------------------
// K2: reduce partials. grid = 1280 x 256. (unchanged from round 2)
// ---------------------------------------------------------------------------
__global__ __launch_bounds__(256) void k2_reduce(
    const float* __restrict__ tpart1, const float* __restrict__ tpart2,
    const float* __restrict__ dpart1, const float* __restrict__ dpart2,
    float* __restrict__ t1, float* __restrict__ t2,
    float* __restrict__ d1, float* __restrict__ d2)
{
    __shared__ float sdata[256];
    const int b = blockIdx.x;
    const int t = threadIdx.x;

    if (b < 256) {
        const float* src = (b < 128) ? tpart1 : tpart2;
        float* dst       = (b < 128) ? t1 : t2;
        const int colbase = (b & 127) * 32;
        const int col = t & 31;
        const int sg = t >> 5;
        float a0 = 0.f, a1 = 0.f, a2 = 0.f, a3 = 0.f;
        #pragma unroll 4
        for (int k = 0; k < 32; k += 4) {
            a0 += src[(size_t)(sg + 8 * (k + 0)) * N + colbase + col];
            a1 += src[(size_t)(sg + 8 * (k + 1)) * N + colbase + col];
            a2 += src[(size_t)(sg + 8 * (k + 2)) * N + colbase + col];
            a3 += src[(size_t)(sg + 8 * (k + 3)) * N + colbase + col];
        }
        sdata[t] = (a0 + a1) + (a2 + a3);
        __syncthreads();
        if (t < 32) {
            float s = 0.f;
            #pragma unroll
            for (int i = 0; i < 8; ++i) s += sdata[i * 32 + t];
            dst[colbase + t] = s;
        }
    } else {
        const int db = b - 256;
        const float* src = (db < 512) ? dpart1 : dpart2;
        float* dst       = (db < 512) ? d1 : d2;
        const int rowbase = (db & 511) * 8;
        const int row = rowbase + (t >> 5);
        const int s = t & 31;
        float v = src[(size_t)row * 32 + s];
        #pragma unroll
        for (int off = 16; off > 0; off >>= 1) v += __shfl_down(v, off, 32);
        if (s == 0) dst[row] = v;
    }
}

// ---------------------------------------------------------------------------
// K3: three circulant matvecs + final combine. 1024 blocks x 4 rows each.
//   Full key staged in padded LDS; x/t1/t2 via float4 (L2-hot).
// ---------------------------------------------------------------------------
__global__ __launch_bounds__(256) void k3_final(
    const float* __restrict__ key, const float* __restrict__ x,
    const float* __restrict__ t1, const float* __restrict__ t2,
    const float* __restrict__ d1, const float* __restrict__ d2,
    const float* __restrict__ o1, const float* __restrict__ o2,
    float* __restrict__ out)
{
    __shared__ float skey[4096 + 128];
    __shared__ float sred[48];                 // [wave][v][row]
    const int t = threadIdx.x;
    const int j0 = blockIdx.x * 4;

    #pragma unroll
    for (int q = 0; q < 16; ++q) {
        const int idx = q * 256 + t;
        skey[idx + (idx >> 5)] = key[idx];
    }
    __syncthreads();

    float acc[4][3];
    #pragma unroll
    for (int r = 0; r < 4; ++r)
        #pragma unroll
        for (int v = 0; v < 3; ++v) acc[r][v] = 0.f;

    #pragma unroll
    for (int q = 0; q < 4; ++q) {
        const int k0 = q * 1024 + 4 * t;
        const float4 xv = *(const float4*)(x + k0);
        const float4 u1 = *(const float4*)(t1 + k0);
        const float4 u2 = *(const float4*)(t2 + k0);
        float kw[7];                           // (k0 + c - j0 - r), c:0..3, r:0..3
        #pragma unroll
        for (int i = 0; i < 7; ++i) {
            const int widx = (k0 - j0 - 3 + i) & MASK;
            kw[i] = skey[widx + (widx >> 5)];
        }
        #pragma unroll
        for (int r = 0; r < 4; ++r) {
            const float kv0 = kw[3 - r], kv1 = kw[4 - r], kv2 = kw[5 - r], kv3 = kw[6 - r];
            acc[r][0] += kv0 * xv.x + kv1 * xv.y + kv2 * xv.z + kv3 * xv.w;
            acc[r][1] += kv0 * u1.x + kv1 * u1.y + kv2 * u1.z + kv3 * u1.w;
            acc[r][2] += kv0 * u2.x + kv1 * u2.y + kv2 * u2.z + kv3 * u2.w;
        }
    }

    float rv[3];
    #pragma unroll
    for (int v = 0; v < 3; ++v)
        rv[v] = greduce4(acc[0][v], acc[1][v], acc[2][v], acc[3][v]);

    const int lane = t & 63, wave = t >> 6, sg = lane >> 4;
    const int off = (0x3120 >> (sg * 4)) & 0xF;  // which row this lane holds
    if ((lane & 15) == 0) {
        #pragma unroll
        for (int v = 0; v < 3; ++v) sred[wave * 12 + v * 4 + off] = rv[v];
    }
    __syncthreads();

    if (t < 4) {
        const int j = j0 + t;
        float vb = 0.f, v1 = 0.f, v2 = 0.f;
        #pragma unroll
        for (int wv = 0; wv < 4; ++wv) {
            vb += sred[wv * 12 + 0 + t];
            v1 += sred[wv * 12 + 4 + t];
            v2 += sred[wv * 12 + 8 + t];
        }
        const float dd1 = d1[j], dd2 = d2[j];
        const float r2 = v1 - dd1 * o1[j];
        const float r4 = v2 - dd2 * o2[j];
        out[j] = (vb - r2 - r4) / dd1;
        if (j == N - 1) out[N] = dd2;          // redun3 = d2[last row]
    }
}

extern "C" void kernel_launch(void* const* d_in, const int* in_sizes, int n_in,
                              void* d_out, int out_size, void* d_ws, size_t ws_size,
                              hipStream_t stream) {
    const float* key = (const float*)d_in[0];
    const float* x   = (const float*)d_in[1];
    const float* km1 = (const float*)d_in[2];
    const float* o1  = (const float*)d_in[3];
    const float* km2 = (const float*)d_in[4];
    const float* o2  = (const float*)d_in[5];
    float* out = (float*)d_out;

    float* ws = (float*)d_ws;
    float* tpart1 = ws;                                  // 256*4096
    float* tpart2 = tpart1 + (size_t)256 * N;            // 256*4096
    float* dpart1 = tpart2 + (size_t)256 * N;            // 4096*32
    float* dpart2 = dpart1 + (size_t)N * 32;             // 4096*32
    float* t1     = dpart2 + (size_t)N * 32;             // 4096
    float* t2     = t1 + N;
    float* d1     = t2 + N;
    float* d2     = d1 + N;

    hipLaunchKernelGGL(k1_fused, dim3(2048), dim3(256), 0, stream,
                       key, km1, km2, o1, o2, tpart1, tpart2, dpart1, dpart2);
    hipLaunchKernelGGL(k2_reduce, dim3(1280), dim3(256), 0, stream,
                       tpart1, tpart2, dpart1, dpart2, t1, t2, d1, d2);
    hipLaunchKernelGGL(k3_final, dim3(1024), dim3(256), 0, stream,
                       key, x, t1, t2, d1, d2, o1, o2, out);
}